// Round 10
// baseline (325.001 us; speedup 1.0000x reference)
//
#include <hip/hip_runtime.h>
#include <hip/hip_bf16.h>
#include <hip/hip_cooperative_groups.h>

namespace cg = cooperative_groups;

#define D 64
#define ED 32
#define NN 50000
#define EE 800000
#define NT64 (EE / 64)   // 12500 64-edge tiles, exact
#define NWN (NN / 16)    // 3125 16-node tiles, exact

#define PREP_N (4 * D * D + D * ED)          // 18432 prep elements
#define NB_SCAN ((NN + 255) / 256)           // 196
#define BLD_BLOCKS 512
#define BLD_THREADS (BLD_BLOCKS * 256)       // 131072
#define BLD_WAVES (BLD_BLOCKS * 4)           // 2048

typedef __attribute__((ext_vector_type(8))) short bf16x8;
typedef __attribute__((ext_vector_type(4))) float f32x4;
typedef __attribute__((ext_vector_type(4))) unsigned uint4v;
typedef __attribute__((ext_vector_type(4))) int int4v;

__device__ __forceinline__ short f2bf(float f) {
    __hip_bfloat16 h = __float2bfloat16(f);
    return *reinterpret_cast<short*>(&h);
}
__device__ __forceinline__ float bfhi2f(unsigned w) { return __uint_as_float(w & 0xFFFF0000u); }
__device__ __forceinline__ float bflo2f(unsigned w) { return __uint_as_float(w << 16); }
__device__ __forceinline__ unsigned packqv(float q, float v) {
    return (unsigned)(unsigned short)f2bf(q) | ((unsigned)(unsigned short)f2bf(v) << 16);
}

// ONE cooperative kernel for the whole build:
//  P0 weight prep + deg/gctr zero | P1 node MFMA transforms + dst histogram |
//  P2 per-256-node exclusive scan with atomic global base | P3 scatter.
__global__ __launch_bounds__(256, 4)
void build_all(const float* __restrict__ x,
               const int* __restrict__ srcI, const int* __restrict__ dstI,
               const float* __restrict__ Wk, const float* __restrict__ Wq,
               const float* __restrict__ Wv, const float* __restrict__ Ws,
               const float* __restrict__ bk, const float* __restrict__ bq,
               const float* __restrict__ bv, const float* __restrict__ bias,
               unsigned short* __restrict__ WnT,
               unsigned short* __restrict__ WgT, unsigned short* __restrict__ WvT,
               float* __restrict__ kx, unsigned* __restrict__ qv, float* __restrict__ out,
               int* __restrict__ deg, int* __restrict__ off, int* __restrict__ gctr,
               unsigned long long* __restrict__ rec) {
    cg::grid_group grid = cg::this_grid();
    __shared__ int s_tmp[256];
    __shared__ int s_base;
    const int tid = blockIdx.x * 256 + threadIdx.x;

    // ---------------- P0: weight prep + zeroing ----------------
    if (tid < 4 * D * D) {
        const int m = tid >> 12, col = (tid >> 6) & 63, k = tid & 63;
        const float* W = (m == 0) ? Ws : (m == 1) ? Wk : (m == 2) ? Wq : Wv;
        WnT[tid] = (unsigned short)f2bf(W[k * D + col]);
    } else if (tid < PREP_N) {
        const int j = tid - 4 * D * D;
        const int c = j >> 5, k = j & 31;
        const size_t o = (size_t)(D + k) * D + c;
        WgT[j] = (unsigned short)f2bf(Wk[o] + Wq[o]);
        WvT[j] = (unsigned short)f2bf(Wv[o]);
    }
    if (tid < NN / 4) ((int4v*)deg)[tid] = (int4v){0, 0, 0, 0};
    if (tid == 0) *gctr = 0;
    grid.sync();

    // ---------------- P1: node transforms (MFMA) + histogram ----------------
    {
        const int lane = threadIdx.x & 63;
        const int lg = lane >> 4, lr = lane & 15;
        for (int wid = tid >> 6; wid < NWN; wid += BLD_WAVES) {
            const int n0 = wid * 16;
            const float* xp = x + (size_t)(n0 + lr) * D + 8 * lg;
            const f32x4 x00 = *(const f32x4*)xp;
            const f32x4 x01 = *(const f32x4*)(xp + 4);
            const f32x4 x10 = *(const f32x4*)(xp + 32);
            const f32x4 x11 = *(const f32x4*)(xp + 36);
            bf16x8 af0, af1;
#pragma unroll
            for (int e = 0; e < 4; ++e) {
                af0[e] = f2bf(x00[e]); af0[e + 4] = f2bf(x01[e]);
                af1[e] = f2bf(x10[e]); af1[e + 4] = f2bf(x11[e]);
            }
            f32x4 acc[4], accQ[4];
#pragma unroll
            for (int m = 0; m < 4; ++m) {
                f32x4* A = (m == 2) ? accQ : acc;
#pragma unroll
                for (int h = 0; h < 4; ++h) {
                    const bf16x8 b0 = *(const bf16x8*)(WnT + (size_t)(m * D + 16 * h + lr) * D + 8 * lg);
                    const bf16x8 b1 = *(const bf16x8*)(WnT + (size_t)(m * D + 16 * h + lr) * D + 32 + 8 * lg);
                    A[h] = __builtin_amdgcn_mfma_f32_16x16x32_bf16(af0, b0, (f32x4)(0.f), 0, 0, 0);
                    A[h] = __builtin_amdgcn_mfma_f32_16x16x32_bf16(af1, b1, A[h], 0, 0, 0);
                }
                if (m == 0) {
#pragma unroll
                    for (int r = 0; r < 4; ++r)
#pragma unroll
                        for (int h = 0; h < 4; ++h)
                            out[(size_t)(n0 + 4 * lg + r) * D + 16 * h + lr] = acc[h][r] + bias[16 * h + lr];
                } else if (m == 1) {
#pragma unroll
                    for (int r = 0; r < 4; ++r)
#pragma unroll
                        for (int h = 0; h < 4; ++h)
                            kx[(size_t)(n0 + 4 * lg + r) * D + 16 * h + lr] = acc[h][r] + bk[16 * h + lr];
                } else if (m == 3) {
#pragma unroll
                    for (int r = 0; r < 4; ++r)
#pragma unroll
                        for (int h = 0; h < 4; ++h)
                            qv[(size_t)(n0 + 4 * lg + r) * D + 16 * h + lr] =
                                packqv(accQ[h][r] + bq[16 * h + lr], acc[h][r] + bv[16 * h + lr]);
                }
            }
        }
        // histogram: 4 edges per thread, int4 NT loads
        for (int q = tid; q < EE / 4; q += BLD_THREADS) {
            const int4v d4 = __builtin_nontemporal_load((const int4v*)(dstI + 4 * q));
#pragma unroll
            for (int r = 0; r < 4; ++r) atomicAdd(&deg[d4[r]], 1);
        }
    }
    grid.sync();

    // ---------------- P2: exclusive scan, block-local + atomic global base ----------------
    if (blockIdx.x < NB_SCAN) {
        const int t = threadIdx.x, i = blockIdx.x * 256 + t;
        const int v = (i < NN) ? deg[i] : 0;
        s_tmp[t] = v;
        __syncthreads();
        for (int d = 1; d < 256; d <<= 1) {
            const int add = (t >= d) ? s_tmp[t - d] : 0;
            __syncthreads();
            s_tmp[t] += add;
            __syncthreads();
        }
        if (t == 255) s_base = atomicAdd(gctr, s_tmp[255]);
        __syncthreads();
        if (i < NN) off[i] = s_base + s_tmp[t] - v;   // final start position
    }
    grid.sync();

    // ---------------- P3: scatter into dst-grouped records ----------------
    for (int q = tid; q < EE / 4; q += BLD_THREADS) {
        const int e = 4 * q;
        const int4v s4 = __builtin_nontemporal_load((const int4v*)(srcI + e));
        const int4v d4 = __builtin_nontemporal_load((const int4v*)(dstI + e));
#pragma unroll
        for (int r = 0; r < 4; ++r) {
            const int s = s4[r], d = d4[r];
            const int p = atomicAdd(&off[d], 1);
            rec[p] = ((unsigned long long)(unsigned)(e + r) << 32)
                   | (unsigned)(s | (d << 16));
        }
    }
}

// Edge-parallel aggregation over dst-grouped edges (unchanged, proven).
__global__ __launch_bounds__(256, 3)
void agg_sorted(const unsigned* __restrict__ rec, const float* __restrict__ ea,
                const unsigned short* __restrict__ WgT, const unsigned short* __restrict__ WvT,
                const float* __restrict__ kx, const unsigned* __restrict__ qv,
                float* __restrict__ out) {
    const int lane = threadIdx.x & 63;
    const int wid  = blockIdx.x * 4 + (threadIdx.x >> 6);   // tile id, grid exact
    const int lg = lane >> 4;
    const int lr = lane & 15;
    const int e0 = wid * 64;

    bf16x8 bg[4], bvf[4];
#pragma unroll
    for (int h = 0; h < 4; ++h) {
        bg[h]  = *(const bf16x8*)(WgT + (size_t)(16 * h + lr) * ED + 8 * lg);
        bvf[h] = *(const bf16x8*)(WvT + (size_t)(16 * h + lr) * ED + 8 * lg);
    }

#pragma unroll
    for (int g = 0; g < 4; ++g) {
        const int gb = e0 + 16 * g;
        const uint4v rA = *(const uint4v*)(rec + 2 * (gb + 4 * lg));
        const uint4v rB = *(const uint4v*)(rec + 2 * (gb + 4 * lg) + 4);
        int dR[4], sR[4];
        dR[0] = (int)(rA.x >> 16); sR[0] = (int)(rA.x & 0xFFFFu);
        dR[1] = (int)(rA.z >> 16); sR[1] = (int)(rA.z & 0xFFFFu);
        dR[2] = (int)(rB.x >> 16); sR[2] = (int)(rB.x & 0xFFFFu);
        dR[3] = (int)(rB.z >> 16); sR[3] = (int)(rB.z & 0xFFFFu);

        const unsigned pl = rec[2 * (gb + lr) + 1];
        const float* ap = ea + (size_t)pl * ED + 8 * lg;
        const f32x4 a0 = __builtin_nontemporal_load((const f32x4*)ap);
        const f32x4 a1 = __builtin_nontemporal_load((const f32x4*)(ap + 4));

        unsigned qg[4][4];
        float    kk[4][4];
#pragma unroll
        for (int r = 0; r < 4; ++r) {
            const unsigned* qp = qv + (size_t)sR[r] * D;
            const float*    kp = kx + (size_t)dR[r] * D;
#pragma unroll
            for (int h = 0; h < 4; ++h) {
                qg[r][h] = qp[16 * h + lr];
                kk[r][h] = kp[16 * h + lr];
            }
        }

        bf16x8 af;
#pragma unroll
        for (int e2 = 0; e2 < 4; ++e2) { af[e2] = f2bf(a0[e2]); af[e2 + 4] = f2bf(a1[e2]); }

        f32x4 accG[4], accV[4];
#pragma unroll
        for (int h = 0; h < 4; ++h) {
            accG[h] = __builtin_amdgcn_mfma_f32_16x16x32_bf16(af, bg[h],  (f32x4)(0.f), 0, 0, 0);
            accV[h] = __builtin_amdgcn_mfma_f32_16x16x32_bf16(af, bvf[h], (f32x4)(0.f), 0, 0, 0);
        }

        float msg[4][4];
#pragma unroll
        for (int r = 0; r < 4; ++r)
#pragma unroll
            for (int h = 0; h < 4; ++h) {
                const float z = accG[h][r] + kk[r][h] + bflo2f(qg[r][h]);
                const float v = accV[h][r] + bfhi2f(qg[r][h]);
                msg[r][h] = v * __builtin_amdgcn_rcpf(1.0f + __expf(-z));
            }

        bool done[4] = {false, false, false, false};
        while (true) {
            int m0 = 0x7FFFFFFF;
#pragma unroll
            for (int r = 0; r < 4; ++r) m0 = min(m0, done[r] ? 0x7FFFFFFF : dR[r]);
            m0 = min(m0, __shfl_xor(m0, 16, 64));
            m0 = min(m0, __shfl_xor(m0, 32, 64));
            if (m0 == 0x7FFFFFFF) break;          // wave-uniform exit
            float sh[4];
#pragma unroll
            for (int h = 0; h < 4; ++h) {
                float a = 0.f;
#pragma unroll
                for (int r = 0; r < 4; ++r) a += (dR[r] == m0) ? msg[r][h] : 0.f;
                a += __shfl_xor(a, 16, 64);
                a += __shfl_xor(a, 32, 64);
                sh[h] = a;
            }
#pragma unroll
            for (int r = 0; r < 4; ++r) done[r] = done[r] || (dR[r] == m0);
            if (lane < 16) {
                float* op = out + (size_t)m0 * D;
#pragma unroll
                for (int h = 0; h < 4; ++h)
                    unsafeAtomicAdd(&op[16 * h + lane], sh[h]);
            }
        }
    }
}

extern "C" void kernel_launch(void* const* d_in, const int* in_sizes, int n_in,
                              void* d_out, int out_size, void* d_ws, size_t ws_size,
                              hipStream_t stream) {
    const float* x    = (const float*)d_in[0];
    const int*   eidx = (const int*)d_in[1];      // [2, E]: row0=src, row1=dst
    const float* eatt = (const float*)d_in[2];
    const float* Wk   = (const float*)d_in[3];
    const float* bk   = (const float*)d_in[4];
    const float* Wq   = (const float*)d_in[5];
    const float* bq   = (const float*)d_in[6];
    const float* Wv   = (const float*)d_in[7];
    const float* bv   = (const float*)d_in[8];
    const float* Ws   = (const float*)d_in[9];
    const float* bias = (const float*)d_in[10];
    float* out = (float*)d_out;

    // workspace carve (offsets keep 16B alignment)
    char* w = (char*)d_ws;
    float*    kx  = (float*)w;            w += (size_t)NN * D * 4;   // 12.8 MB
    unsigned* qv  = (unsigned*)w;         w += (size_t)NN * D * 4;   // 12.8 MB
    unsigned short* WnT = (unsigned short*)w;  w += 4 * D * D * 2;   // 32 KB
    unsigned short* WgT = (unsigned short*)w;  w += D * ED * 2;      // 4 KB
    unsigned short* WvT = (unsigned short*)w;  w += D * ED * 2;      // 4 KB
    int* deg  = (int*)w;                  w += (size_t)NN * 4;       // 200 KB
    int* off  = (int*)w;                  w += (size_t)NN * 4;       // 200 KB
    int* gctr = (int*)w;                  w += 16;                   // 16 B
    unsigned long long* rec = (unsigned long long*)w;                // 6.4 MB

    const int* srcI = eidx;
    const int* dstI = eidx + EE;

    void* args[] = { (void*)&x, (void*)&srcI, (void*)&dstI,
                     (void*)&Wk, (void*)&Wq, (void*)&Wv, (void*)&Ws,
                     (void*)&bk, (void*)&bq, (void*)&bv, (void*)&bias,
                     (void*)&WnT, (void*)&WgT, (void*)&WvT,
                     (void*)&kx, (void*)&qv, (void*)&out,
                     (void*)&deg, (void*)&off, (void*)&gctr, (void*)&rec };
    hipLaunchCooperativeKernel((const void*)build_all, dim3(BLD_BLOCKS), dim3(256),
                               args, 0, stream);

    // aggregation: 12500 waves = 3125 blocks (unchanged control)
    agg_sorted<<<NT64 / 4, 256, 0, stream>>>((const unsigned*)rec, eatt,
                                             WgT, WvT, kx, qv, out);
}

// Round 11
// 174.700 us; speedup vs baseline: 1.8603x; 1.8603x over previous
//
#include <hip/hip_runtime.h>
#include <hip/hip_bf16.h>

#define D 64
#define ED 32
#define NN 50000
#define EE 800000
#define NT64 (EE / 64)   // 12500 64-edge tiles, exact
#define NWN (NN / 16)    // 3125 16-node tiles, exact
#define NB_NODE ((NWN + 3) / 4)              // 782
#define NB_HIST ((EE / 4 + 255) / 256)       // 782 (EE % 4 == 0)
#define NB_SCAN ((NN + 255) / 256)           // 196

typedef __attribute__((ext_vector_type(8))) short bf16x8;
typedef __attribute__((ext_vector_type(4))) float f32x4;
typedef __attribute__((ext_vector_type(4))) unsigned uint4v;
typedef __attribute__((ext_vector_type(4))) int int4v;

__device__ __forceinline__ short f2bf(float f) {
    __hip_bfloat16 h = __float2bfloat16(f);
    return *reinterpret_cast<short*>(&h);
}
__device__ __forceinline__ float bfhi2f(unsigned w) { return __uint_as_float(w & 0xFFFF0000u); }
__device__ __forceinline__ float bflo2f(unsigned w) { return __uint_as_float(w << 16); }
__device__ __forceinline__ unsigned packqv(float q, float v) {
    return (unsigned)(unsigned short)f2bf(q) | ((unsigned)(unsigned short)f2bf(v) << 16);
}

// node-part GEMM helper: builds B-frags straight from f32 W (L2-hot 16KB)
__device__ __forceinline__ void nmm(const float* __restrict__ W, int lr, int lg,
                                    bf16x8 af0, bf16x8 af1, f32x4 acc[4]) {
#pragma unroll
    for (int h = 0; h < 4; ++h) {
        bf16x8 b0, b1;
#pragma unroll
        for (int e = 0; e < 8; ++e) {
            b0[e] = f2bf(W[(8 * lg + e) * D + 16 * h + lr]);
            b1[e] = f2bf(W[(32 + 8 * lg + e) * D + 16 * h + lr]);
        }
        acc[h] = __builtin_amdgcn_mfma_f32_16x16x32_bf16(af0, b0, (f32x4)(0.f), 0, 0, 0);
        acc[h] = __builtin_amdgcn_mfma_f32_16x16x32_bf16(af1, b1, acc[h], 0, 0, 0);
    }
}

// Mega-kernel: node MFMA transforms + dst histogram (+ WgT/WvT prep in hist block 0).
__global__ __launch_bounds__(256, 4)
void node_hist(const float* __restrict__ x,
               const float* __restrict__ Wk, const float* __restrict__ Wq,
               const float* __restrict__ Wv, const float* __restrict__ Ws,
               const float* __restrict__ bk, const float* __restrict__ bq,
               const float* __restrict__ bv, const float* __restrict__ bias,
               float* __restrict__ kx, unsigned* __restrict__ qv, float* __restrict__ out,
               const int* __restrict__ dstI, int* __restrict__ deg,
               unsigned short* __restrict__ WgT, unsigned short* __restrict__ WvT) {
    const int b = blockIdx.x;
    if (b >= NB_NODE) {
        const int hb = b - NB_NODE;
        if (hb == 0) {
            // edge-weight frag tables for agg (agg launches later; no race)
            for (int j = threadIdx.x; j < D * ED; j += 256) {
                const int c = j >> 5, k = j & 31;
                const size_t o = (size_t)(D + k) * D + c;
                WgT[j] = (unsigned short)f2bf(Wk[o] + Wq[o]);
                WvT[j] = (unsigned short)f2bf(Wv[o]);
            }
        }
        // histogram: 4 edges per thread, int4 NT loads
        const int t = hb * 256 + threadIdx.x;
        const int e = 4 * t;
        if (e + 4 <= EE) {
            const int4v d4 = __builtin_nontemporal_load((const int4v*)(dstI + e));
#pragma unroll
            for (int r = 0; r < 4; ++r) atomicAdd(&deg[d4[r]], 1);
        }
        return;
    }
    // ---- node transforms: 16 nodes per wave ----
    const int lane = threadIdx.x & 63;
    const int wid  = b * 4 + (threadIdx.x >> 6);
    if (wid >= NWN) return;
    const int lg = lane >> 4, lr = lane & 15;
    const int n0 = wid * 16;

    const float* xp = x + (size_t)(n0 + lr) * D + 8 * lg;
    const f32x4 x00 = *(const f32x4*)xp;
    const f32x4 x01 = *(const f32x4*)(xp + 4);
    const f32x4 x10 = *(const f32x4*)(xp + 32);
    const f32x4 x11 = *(const f32x4*)(xp + 36);
    bf16x8 af0, af1;
#pragma unroll
    for (int e = 0; e < 4; ++e) {
        af0[e] = f2bf(x00[e]); af0[e + 4] = f2bf(x01[e]);
        af1[e] = f2bf(x10[e]); af1[e + 4] = f2bf(x11[e]);
    }

    f32x4 acc[4], accQ[4];

    nmm(Ws, lr, lg, af0, af1, acc);          // skip + bias (initializes out)
#pragma unroll
    for (int r = 0; r < 4; ++r)
#pragma unroll
        for (int h = 0; h < 4; ++h)
            out[(size_t)(n0 + 4 * lg + r) * D + 16 * h + lr] = acc[h][r] + bias[16 * h + lr];

    nmm(Wk, lr, lg, af0, af1, acc);          // key
#pragma unroll
    for (int r = 0; r < 4; ++r)
#pragma unroll
        for (int h = 0; h < 4; ++h)
            kx[(size_t)(n0 + 4 * lg + r) * D + 16 * h + lr] = acc[h][r] + bk[16 * h + lr];

    nmm(Wq, lr, lg, af0, af1, accQ);         // query
    nmm(Wv, lr, lg, af0, af1, acc);          // value
#pragma unroll
    for (int r = 0; r < 4; ++r)
#pragma unroll
        for (int h = 0; h < 4; ++h)
            qv[(size_t)(n0 + 4 * lg + r) * D + 16 * h + lr] =
                packqv(accQ[h][r] + bq[16 * h + lr], acc[h][r] + bv[16 * h + lr]);
}

// Exclusive scan with atomic global base: off[i] = final start of node i's run.
__global__ void k_scanA(const int* __restrict__ deg, int* __restrict__ off,
                        int* __restrict__ gctr) {
    __shared__ int s_tmp[256];
    __shared__ int s_base;
    const int t = threadIdx.x, i = blockIdx.x * 256 + t;
    const int v = (i < NN) ? deg[i] : 0;
    s_tmp[t] = v;
    __syncthreads();
    for (int d = 1; d < 256; d <<= 1) {
        const int add = (t >= d) ? s_tmp[t - d] : 0;
        __syncthreads();
        s_tmp[t] += add;
        __syncthreads();
    }
    if (t == 255) s_base = atomicAdd(gctr, s_tmp[255]);
    __syncthreads();
    if (i < NN) off[i] = s_base + s_tmp[t] - v;
}

// Scatter, 4 edges/thread; off holds final global positions (consumed by fetch-add).
__global__ void k_scatter4(const int* __restrict__ srcI, const int* __restrict__ dstI,
                           int* __restrict__ off, unsigned long long* __restrict__ rec) {
    const int t = blockIdx.x * 256 + threadIdx.x;
    const int e = 4 * t;
    if (e + 4 > EE) return;
    const int4v s4 = __builtin_nontemporal_load((const int4v*)(srcI + e));
    const int4v d4 = __builtin_nontemporal_load((const int4v*)(dstI + e));
#pragma unroll
    for (int r = 0; r < 4; ++r) {
        const int s = s4[r], d = d4[r];
        const int p = atomicAdd(&off[d], 1);
        rec[p] = ((unsigned long long)(unsigned)(e + r) << 32)
               | (unsigned)(s | (d << 16));
    }
}

// Edge-parallel aggregation over dst-grouped edges. 2-group load batching:
// all loads of a group PAIR issue before either group's compute (deeper MLP).
__global__ __launch_bounds__(256, 2)
void agg_sorted(const unsigned* __restrict__ rec, const float* __restrict__ ea,
                const unsigned short* __restrict__ WgT, const unsigned short* __restrict__ WvT,
                const float* __restrict__ kx, const unsigned* __restrict__ qv,
                float* __restrict__ out) {
    const int lane = threadIdx.x & 63;
    const int wid  = blockIdx.x * 4 + (threadIdx.x >> 6);   // tile id, grid exact
    const int lg = lane >> 4;
    const int lr = lane & 15;
    const int e0 = wid * 64;

    bf16x8 bg[4], bvf[4];
#pragma unroll
    for (int h = 0; h < 4; ++h) {
        bg[h]  = *(const bf16x8*)(WgT + (size_t)(16 * h + lr) * ED + 8 * lg);
        bvf[h] = *(const bf16x8*)(WvT + (size_t)(16 * h + lr) * ED + 8 * lg);
    }

#pragma unroll
    for (int gp = 0; gp < 2; ++gp) {
        const int gbA = e0 + 32 * gp;        // first group of the pair
        const int gbB = gbA + 16;            // second group

        // ---- LOAD PHASE (both groups) ----
        const uint4v rA0 = *(const uint4v*)(rec + 2 * (gbA + 4 * lg));
        const uint4v rA1 = *(const uint4v*)(rec + 2 * (gbA + 4 * lg) + 4);
        const uint4v rB0 = *(const uint4v*)(rec + 2 * (gbB + 4 * lg));
        const uint4v rB1 = *(const uint4v*)(rec + 2 * (gbB + 4 * lg) + 4);
        int dA[4], sA[4], dB[4], sB[4];
        dA[0] = (int)(rA0.x >> 16); sA[0] = (int)(rA0.x & 0xFFFFu);
        dA[1] = (int)(rA0.z >> 16); sA[1] = (int)(rA0.z & 0xFFFFu);
        dA[2] = (int)(rA1.x >> 16); sA[2] = (int)(rA1.x & 0xFFFFu);
        dA[3] = (int)(rA1.z >> 16); sA[3] = (int)(rA1.z & 0xFFFFu);
        dB[0] = (int)(rB0.x >> 16); sB[0] = (int)(rB0.x & 0xFFFFu);
        dB[1] = (int)(rB0.z >> 16); sB[1] = (int)(rB0.z & 0xFFFFu);
        dB[2] = (int)(rB1.x >> 16); sB[2] = (int)(rB1.x & 0xFFFFu);
        dB[3] = (int)(rB1.z >> 16); sB[3] = (int)(rB1.z & 0xFFFFu);

        const unsigned plA = rec[2 * (gbA + lr) + 1];
        const unsigned plB = rec[2 * (gbB + lr) + 1];
        const float* apA = ea + (size_t)plA * ED + 8 * lg;
        const float* apB = ea + (size_t)plB * ED + 8 * lg;
        const f32x4 a0A = __builtin_nontemporal_load((const f32x4*)apA);
        const f32x4 a1A = __builtin_nontemporal_load((const f32x4*)(apA + 4));
        const f32x4 a0B = __builtin_nontemporal_load((const f32x4*)apB);
        const f32x4 a1B = __builtin_nontemporal_load((const f32x4*)(apB + 4));

        unsigned qgA[4][4], qgB[4][4];
        float    kkA[4][4], kkB[4][4];
#pragma unroll
        for (int r = 0; r < 4; ++r) {
            const unsigned* qpA = qv + (size_t)sA[r] * D;
            const float*    kpA = kx + (size_t)dA[r] * D;
            const unsigned* qpB = qv + (size_t)sB[r] * D;
            const float*    kpB = kx + (size_t)dB[r] * D;
#pragma unroll
            for (int h = 0; h < 4; ++h) {
                qgA[r][h] = qpA[16 * h + lr];
                kkA[r][h] = kpA[16 * h + lr];
                qgB[r][h] = qpB[16 * h + lr];
                kkB[r][h] = kpB[16 * h + lr];
            }
        }

        // ---- COMPUTE PHASE ----
        bf16x8 afA, afB;
#pragma unroll
        for (int e2 = 0; e2 < 4; ++e2) {
            afA[e2] = f2bf(a0A[e2]); afA[e2 + 4] = f2bf(a1A[e2]);
            afB[e2] = f2bf(a0B[e2]); afB[e2 + 4] = f2bf(a1B[e2]);
        }

        f32x4 accGA[4], accVA[4], accGB[4], accVB[4];
#pragma unroll
        for (int h = 0; h < 4; ++h) {
            accGA[h] = __builtin_amdgcn_mfma_f32_16x16x32_bf16(afA, bg[h],  (f32x4)(0.f), 0, 0, 0);
            accVA[h] = __builtin_amdgcn_mfma_f32_16x16x32_bf16(afA, bvf[h], (f32x4)(0.f), 0, 0, 0);
            accGB[h] = __builtin_amdgcn_mfma_f32_16x16x32_bf16(afB, bg[h],  (f32x4)(0.f), 0, 0, 0);
            accVB[h] = __builtin_amdgcn_mfma_f32_16x16x32_bf16(afB, bvf[h], (f32x4)(0.f), 0, 0, 0);
        }

        float msgA[4][4], msgB[4][4];
#pragma unroll
        for (int r = 0; r < 4; ++r)
#pragma unroll
            for (int h = 0; h < 4; ++h) {
                const float zA = accGA[h][r] + kkA[r][h] + bflo2f(qgA[r][h]);
                const float vA = accVA[h][r] + bfhi2f(qgA[r][h]);
                msgA[r][h] = vA * __builtin_amdgcn_rcpf(1.0f + __expf(-zA));
                const float zB = accGB[h][r] + kkB[r][h] + bflo2f(qgB[r][h]);
                const float vB = accVB[h][r] + bfhi2f(qgB[r][h]);
                msgB[r][h] = vB * __builtin_amdgcn_rcpf(1.0f + __expf(-zB));
            }

        // ---- segmented reduce, group A then group B ----
#pragma unroll
        for (int half = 0; half < 2; ++half) {
            const int*  dR  = half ? dB : dA;
            float (*msg)[4] = half ? msgB : msgA;
            bool done[4] = {false, false, false, false};
            while (true) {
                int m0 = 0x7FFFFFFF;
#pragma unroll
                for (int r = 0; r < 4; ++r) m0 = min(m0, done[r] ? 0x7FFFFFFF : dR[r]);
                m0 = min(m0, __shfl_xor(m0, 16, 64));
                m0 = min(m0, __shfl_xor(m0, 32, 64));
                if (m0 == 0x7FFFFFFF) break;          // wave-uniform exit
                float sh[4];
#pragma unroll
                for (int h = 0; h < 4; ++h) {
                    float a = 0.f;
#pragma unroll
                    for (int r = 0; r < 4; ++r) a += (dR[r] == m0) ? msg[r][h] : 0.f;
                    a += __shfl_xor(a, 16, 64);
                    a += __shfl_xor(a, 32, 64);
                    sh[h] = a;
                }
#pragma unroll
                for (int r = 0; r < 4; ++r) done[r] = done[r] || (dR[r] == m0);
                if (lane < 16) {
                    float* op = out + (size_t)m0 * D;
#pragma unroll
                    for (int h = 0; h < 4; ++h)
                        unsafeAtomicAdd(&op[16 * h + lane], sh[h]);
                }
            }
        }
    }
}

extern "C" void kernel_launch(void* const* d_in, const int* in_sizes, int n_in,
                              void* d_out, int out_size, void* d_ws, size_t ws_size,
                              hipStream_t stream) {
    const float* x    = (const float*)d_in[0];
    const int*   eidx = (const int*)d_in[1];      // [2, E]: row0=src, row1=dst
    const float* eatt = (const float*)d_in[2];
    const float* Wk   = (const float*)d_in[3];
    const float* bk   = (const float*)d_in[4];
    const float* Wq   = (const float*)d_in[5];
    const float* bq   = (const float*)d_in[6];
    const float* Wv   = (const float*)d_in[7];
    const float* bv   = (const float*)d_in[8];
    const float* Ws   = (const float*)d_in[9];
    const float* bias = (const float*)d_in[10];
    float* out = (float*)d_out;

    // workspace carve (offsets keep 16B alignment; deg+gctr contiguous for one memset)
    char* w = (char*)d_ws;
    float*    kx  = (float*)w;            w += (size_t)NN * D * 4;   // 12.8 MB
    unsigned* qv  = (unsigned*)w;         w += (size_t)NN * D * 4;   // 12.8 MB
    unsigned short* WgT = (unsigned short*)w;  w += D * ED * 2;      // 4 KB
    unsigned short* WvT = (unsigned short*)w;  w += D * ED * 2;      // 4 KB
    int* deg  = (int*)w;                  w += (size_t)NN * 4;       // 200 KB
    int* gctr = (int*)w;                  w += 16;                   // 16 B
    int* off  = (int*)w;                  w += (size_t)NN * 4;       // 200 KB
    unsigned long long* rec = (unsigned long long*)w;                // 6.4 MB

    const int* srcI = eidx;
    const int* dstI = eidx + EE;

    // 1) zero deg + gctr (one memset node)
    hipMemsetAsync(deg, 0, (size_t)NN * 4 + 16, stream);
    // 2) node transforms + histogram (+ WgT/WvT prep)
    node_hist<<<NB_NODE + NB_HIST, 256, 0, stream>>>(x, Wk, Wq, Wv, Ws,
                                                     bk, bq, bv, bias,
                                                     kx, qv, out, dstI, deg,
                                                     WgT, WvT);
    // 3) scan with atomic global base
    k_scanA<<<NB_SCAN, 256, 0, stream>>>(deg, off, gctr);
    // 4) scatter into dst-grouped records
    k_scatter4<<<NB_HIST, 256, 0, stream>>>(srcI, dstI, off, rec);
    // 5) aggregation
    agg_sorted<<<NT64 / 4, 256, 0, stream>>>((const unsigned*)rec, eatt,
                                             WgT, WvT, kx, qv, out);
}